// Round 2
// baseline (1025.165 us; speedup 1.0000x reference)
//
#include <hip/hip_runtime.h>
#include <math.h>

// Problem constants
#define BB 16
#define TT 4096
#define DD 512
#define LOUT 512

typedef __attribute__((ext_vector_type(8))) _Float16 half8;
typedef __attribute__((ext_vector_type(4))) float floatx4;

// ---------------------------------------------------------------------------
// Workspace layout (bytes):
//   A_hi    : _Float16[33554432] @ 0          (hidden hi split)
//   A_lo    : _Float16[33554432] @ 67108864   (hidden lo split)
//   B_hi    : _Float16[786432]   @ 134217728  (conv_w hi, [tap][c][i])
//   B_lo    : _Float16[786432]   @ 135790592
//   a_pre   : float[65536]       @ 137363456
//   w_main  : float[65536]       @ 137625600
//   fire_pos: int[16384]         @ 137887744
//   Fcount  : int[16]            @ 137953280
//   zpage16 : _Float16[512]      @ 137953344  (zero page, conv halo rows)
// ---------------------------------------------------------------------------

__global__ void zero_ws(float* __restrict__ a_pre, _Float16* __restrict__ zp) {
    int idx = blockIdx.x * 256 + threadIdx.x;
    if (idx < 65536) a_pre[idx] = 0.f;
    if (idx < 512)   zp[idx] = (_Float16)0.f;
}

// hidden fp32 -> f16 hi + f16 lo (x = hi + lo + O(2^-22 x))
__global__ void split_hidden(const float* __restrict__ hidden,
                             _Float16* __restrict__ A_hi,
                             _Float16* __restrict__ A_lo) {
    int idx = blockIdx.x * 256 + threadIdx.x;    // 4194304 threads, 8 elems each
    const float4* src = (const float4*)(hidden + 8 * (size_t)idx);
    float4 v0 = src[0], v1 = src[1];
    float x[8] = {v0.x, v0.y, v0.z, v0.w, v1.x, v1.y, v1.z, v1.w};
    _Float16 hi[8], lo[8];
    #pragma unroll
    for (int j = 0; j < 8; j++) {
        hi[j] = (_Float16)x[j];
        lo[j] = (_Float16)(x[j] - (float)hi[j]);
    }
    *(half8*)(A_hi + 8 * (size_t)idx) = *(half8*)hi;
    *(half8*)(A_lo + 8 * (size_t)idx) = *(half8*)lo;
}

// conv_w[c][i][tap] fp32 -> B_hi/B_lo [tap][c][i] f16 (B^T layout: rows=c, cols=i)
__global__ void repack_wsplit(const float* __restrict__ conv_w,
                              _Float16* __restrict__ B_hi,
                              _Float16* __restrict__ B_lo) {
    int idx = blockIdx.x * 256 + threadIdx.x;    // over 786432
    if (idx < 786432) {
        int tap = idx / 262144;
        int rem = idx - tap * 262144;
        int c = rem >> 9;
        int i = rem & 511;
        float v = conv_w[(c * 512 + i) * 3 + tap];
        _Float16 h = (_Float16)v;
        B_hi[idx] = h;
        B_lo[idx] = (_Float16)(v - (float)h);
    }
}

#define GLL16(g, l) __builtin_amdgcn_global_load_lds( \
    (const __attribute__((address_space(1))) void*)(g), \
    (__attribute__((address_space(3))) void*)(l), 16, 0, 0)

// ---------------------------------------------------------------------------
// Double-buffered split-f16 conv-GEMM, counted-vmcnt pipeline (T3/T4).
// Block tile 256(M) x 64(N), 4 waves, wave tile 64x64 = 4x4 frags of 16x16x32.
// LDS holds ONLY the hi operands (Ahi 272x64B + Bhi 3tapx64x64B = 29696 B),
// double-buffered = 59392 B -> 2 blocks/CU. Per kc:
//   STAGE(kc+1 -> buf^1)  [29 GLL16 units across 4 waves]
//   3 taps x { prefetch next lo-frags (global->VGPR, L1/L2-hot),
//              ds_read ah/bh, 48 MFMA (hh, lo*bh, ah*lo) }
//   s_waitcnt vmcnt(8) (never 0) ; raw s_barrier     <- no drain stall
// A_lo/B_lo frags are read direct from global: B is wave/block-shared (L1),
// A_lo taps overlap 3x (L1) -> LDS read traffic + conflicts halve.
// XOR chunk swizzle on hi: logical chunk c of row r at phys c^(r&3); staging
// pre-swizzles the per-lane GLOBAL src (LDS dest linear), reads apply same XOR.
// ---------------------------------------------------------------------------

#define STAGE(KBX, WROFF)                                                   \
  do {                                                                      \
    _Pragma("unroll")                                                       \
    for (int j_ = 0; j_ < 8; j_++)                                          \
      if (w + 4 * j_ < 29)                                                  \
        GLL16(wsb + (size_t)(sgoff[j_] + (KBX)), lds + (WROFF) + sloff[j_]);\
  } while (0)

#define PREF(DA, DB, TI, KBX)                                               \
  do {                                                                      \
    _Pragma("unroll")                                                       \
    for (int i_ = 0; i_ < 4; i_++) {                                        \
      DA[i_] = *(const half8*)(wsb + (size_t)(alo_off[(TI)*4 + i_] + (KBX)));\
      DB[i_] = *(const half8*)(wsb + (size_t)(blo_off[(TI)*4 + i_] + (KBX)));\
    }                                                                       \
  } while (0)

#define TAPC(TAP, RDOFF, LA, LB)                                            \
  do {                                                                      \
    half8 ah_[4], bh_[4];                                                   \
    _Pragma("unroll")                                                       \
    for (int i_ = 0; i_ < 4; i_++) {                                        \
      ah_[i_] = *(const half8*)(lds + (RDOFF) + aoff[(TAP)*4 + i_]);        \
      bh_[i_] = *(const half8*)(lds + (RDOFF) + 17408 + (TAP)*4096 + boff[i_]); \
    }                                                                       \
    __builtin_amdgcn_s_setprio(1);                                          \
    _Pragma("unroll")                                                       \
    for (int mi_ = 0; mi_ < 4; mi_++)                                       \
      _Pragma("unroll")                                                     \
      for (int ni_ = 0; ni_ < 4; ni_++)                                     \
        acc[mi_][ni_] = __builtin_amdgcn_mfma_f32_16x16x32_f16(             \
            ah_[mi_], bh_[ni_], acc[mi_][ni_], 0, 0, 0);                    \
    _Pragma("unroll")                                                       \
    for (int mi_ = 0; mi_ < 4; mi_++)                                       \
      _Pragma("unroll")                                                     \
      for (int ni_ = 0; ni_ < 4; ni_++)                                     \
        acc[mi_][ni_] = __builtin_amdgcn_mfma_f32_16x16x32_f16(             \
            LA[mi_], bh_[ni_], acc[mi_][ni_], 0, 0, 0);                     \
    _Pragma("unroll")                                                       \
    for (int mi_ = 0; mi_ < 4; mi_++)                                       \
      _Pragma("unroll")                                                     \
      for (int ni_ = 0; ni_ < 4; ni_++)                                     \
        acc[mi_][ni_] = __builtin_amdgcn_mfma_f32_16x16x32_f16(             \
            ah_[mi_], LB[ni_], acc[mi_][ni_], 0, 0, 0);                     \
    __builtin_amdgcn_s_setprio(0);                                          \
  } while (0)

#define HALFKC(KB, RDOFF, WROFF, DOSTAGE, DONEXT, CA, CB, NA, NB)           \
  do {                                                                      \
    if (DOSTAGE) STAGE((KB) + 64, WROFF);                                   \
    PREF(NA, NB, 1, KB);                                                    \
    TAPC(0, RDOFF, CA, CB);                                                 \
    PREF(CA, CB, 2, KB);                                                    \
    TAPC(1, RDOFF, NA, NB);                                                 \
    if (DONEXT) PREF(NA, NB, 0, (KB) + 64);                                 \
    TAPC(2, RDOFF, CA, CB);                                                 \
    asm volatile("s_waitcnt vmcnt(8)" ::: "memory");                        \
    __builtin_amdgcn_sched_barrier(0);                                      \
    __builtin_amdgcn_s_barrier();                                           \
    __builtin_amdgcn_sched_barrier(0);                                      \
  } while (0)

__launch_bounds__(256, 2)
__global__ void mfma_gemm(const char* __restrict__ wsb,
                          const float* __restrict__ conv_b,
                          const float* __restrict__ out_w,
                          float* __restrict__ a_pre) {
    __shared__ __align__(128) char lds[59392];

    const int tid  = threadIdx.x;
    const int w    = tid >> 6;            // wave 0..3 = M sub-tile
    const int lane = tid & 63;

    // XCD-chunked swizzle: all 8 N-tiles of an M-tile co-resident on one XCD.
    const int bid = blockIdx.x;
    const int swz = (bid & 7) * 256 + (bid >> 3);
    const int nt  = swz & 7;
    const int mt  = swz >> 3;
    const int b   = mt >> 4;
    const int t0  = (mt & 15) << 8;
    const int c0  = nt << 6;

    const int srow = lane >> 2;           // staging: lane -> row in unit
    const int schk = lane & 3;

    // ---- staging descriptors: 29 GLL16 units (Ahi u0..16, Bhi tapx4) ----
    int sgoff[8], sloff[8];
    #pragma unroll
    for (int j = 0; j < 8; j++) {
        const int g = w + 4 * j;
        int so = 137953344, lo = 0;
        if (g < 29) {
            if (g < 17) {                              // Ahi unit u = g
                const int r  = 16 * g + srow;          // LDS row 0..271
                const int t  = t0 - 1 + r;
                const int sw = (schk ^ (r & 3)) << 4;  // pre-swizzled chunk
                so = (t >= 0 && t < TT) ? (b * TT + t) * 1024 + sw
                                        : 137953344 + sw;
                lo = g * 1024;
            } else {                                   // Bhi units
                const int h  = g - 17;
                const int tp = h >> 2;
                const int u  = h & 3;
                const int r  = 16 * u + srow;
                const int sw = (schk ^ (r & 3)) << 4;
                so = 134217728 + tp * 524288 + (c0 + r) * 1024 + sw;
                lo = 17408 + tp * 4096 + u * 1024;
            }
        }
        sgoff[j] = so;
        sloff[j] = lo;
    }

    // ---- ds_read frag offsets (within one buffer; swizzled read) ----
    int aoff[12], boff[4];
    #pragma unroll
    for (int tap = 0; tap < 3; tap++)
        #pragma unroll
        for (int i = 0; i < 4; i++) {
            const int ra = 64 * w + 16 * i + (lane & 15) + tap;
            aoff[tap * 4 + i] = ra * 64 + (((lane >> 4) ^ (ra & 3)) << 4);
        }
    #pragma unroll
    for (int i = 0; i < 4; i++) {
        const int rb = 16 * i + (lane & 15);
        boff[i] = rb * 64 + (((lane >> 4) ^ (rb & 3)) << 4);
    }

    // ---- direct-global lo-frag byte offsets (into wsb) ----
    int alo_off[12], blo_off[12];
    #pragma unroll
    for (int tap = 0; tap < 3; tap++)
        #pragma unroll
        for (int i = 0; i < 4; i++) {
            const int ra = 64 * w + 16 * i + (lane & 15) + tap;
            const int t  = t0 - 1 + ra;
            alo_off[tap * 4 + i] = (t >= 0 && t < TT)
                ? 67108864 + (b * TT + t) * 1024 + ((lane >> 4) << 4)
                : 137953344 + ((lane >> 4) << 4);
            const int rb = 16 * i + (lane & 15);
            blo_off[tap * 4 + i] = 135790592 + tap * 524288
                                   + (c0 + rb) * 1024 + ((lane >> 4) << 4);
        }

    floatx4 acc[4][4];
    #pragma unroll
    for (int mi = 0; mi < 4; mi++)
        #pragma unroll
        for (int ni = 0; ni < 4; ni++)
            acc[mi][ni] = (floatx4)(0.f);

    // epilogue constants: col n = c0 + 16*ni + (lane&15)
    float u_n[4], cb_n[4];
    #pragma unroll
    for (int ni = 0; ni < 4; ni++) {
        int n = c0 + 16 * ni + (lane & 15);
        u_n[ni]  = out_w[n];
        cb_n[ni] = conv_b[n];
    }

    half8 pa0[4], pb0[4], pa1[4], pb1[4];

    // ---- prologue: stage kc0 -> buf0, prefetch lo (kc0, tap0) ----
    STAGE(0, 0);
    PREF(pa0, pb0, 0, 0);
    __syncthreads();

    // ---- main loop: 16 kc, unrolled x2 for buffer parity ----
    for (int kp = 0; kp < 8; kp++) {
        const int KB = kp * 128;
        HALFKC(KB,      0,     29696, 1,        1,        pa0, pb0, pa1, pb1);
        HALFKC(KB + 64, 29696, 0,     (kp < 7), (kp < 7), pa1, pb1, pa0, pb0);
    }

    // epilogue: s[mi][reg] = sum_ni relu(acc + cb)*u ; reduce over lane&15 ; atomic
    float s[4][4];
    #pragma unroll
    for (int mi = 0; mi < 4; mi++)
        #pragma unroll
        for (int rg = 0; rg < 4; rg++) {
            float t = 0.f;
            #pragma unroll
            for (int ni = 0; ni < 4; ni++) {
                float y = acc[mi][ni][rg] + cb_n[ni];
                y = y > 0.f ? y : 0.f;
                t = fmaf(y, u_n[ni], t);
            }
            s[mi][rg] = t;
        }
    #pragma unroll
    for (int mi = 0; mi < 4; mi++)
        #pragma unroll
        for (int rg = 0; rg < 4; rg++) {
            #pragma unroll
            for (int off = 1; off < 16; off <<= 1)
                s[mi][rg] += __shfl_xor(s[mi][rg], off);
        }
    if ((lane & 15) == 0) {
        const int q = lane >> 4;
        #pragma unroll
        for (int mi = 0; mi < 4; mi++)
            #pragma unroll
            for (int rg = 0; rg < 4; rg++) {
                int m = 64 * w + 16 * mi + 4 * q + rg;
                atomicAdd(&a_pre[b * TT + t0 + m], s[mi][rg]);
            }
    }
}

// Per-batch: sigmoid -> token_num -> rescale -> sequential CIF scan (pipelined).
__global__ void cif_scan(const float* __restrict__ a_pre,
                         const float* __restrict__ mask,
                         const float* __restrict__ tll,
                         const float* __restrict__ out_bias,
                         float* __restrict__ out_tn,
                         float* __restrict__ out_alphas,
                         float* __restrict__ out_peak,
                         float* __restrict__ w_main,
                         int* __restrict__ fire_pos,
                         int* __restrict__ Fcount) {
    __shared__ float alpha_s[TT];
    __shared__ float wm_s[TT];
    __shared__ float fires_s[TT];
    __shared__ int   fp_s[1024];
    __shared__ double red[256];
    __shared__ float ratio_s;
    __shared__ int   F_sh;

    const int b = blockIdx.x;
    const int tid = threadIdx.x;
    const float ob = out_bias[0];

    double lsum = 0.0;
    for (int t = tid; t < TT; t += 256) {
        float a = a_pre[b * TT + t] + ob;
        float e = expf(-fabsf(a));
        float sg = (a >= 0.f) ? (1.f / (1.f + e)) : (e / (1.f + e));
        float af = sg;
        af = af > 0.f ? af : 0.f;
        af = af * mask[b * TT + t];
        alpha_s[t] = af;
        lsum += (double)af;
    }
    red[tid] = lsum;
    __syncthreads();
    for (int off = 128; off > 0; off >>= 1) {
        if (tid < off) red[tid] += red[tid + off];
        __syncthreads();
    }
    if (tid == 0) {
        float tn = (float)red[0];
        out_tn[b] = tn;
        ratio_s = tll[b] / tn;
    }
    __syncthreads();
    const float ratio = ratio_s;
    for (int t = tid; t < TT; t += 256) {
        float a = alpha_s[t] * ratio;
        alpha_s[t] = a;
        out_alphas[b * TT + t] = a;
    }
    __syncthreads();

    if (tid == 0) {
        float I = 0.f;
        int F = 0;
        float4 n0 = *(const float4*)&alpha_s[0];
        float4 n1 = *(const float4*)&alpha_s[4];
        for (int t8 = 0; t8 < TT; t8 += 8) {
            float av[8];
            *(float4*)&av[0] = n0;
            *(float4*)&av[4] = n1;
            if (t8 + 8 < TT) {
                n0 = *(const float4*)&alpha_s[t8 + 8];
                n1 = *(const float4*)&alpha_s[t8 + 12];
            }
            #pragma unroll
            for (int j = 0; j < 8; j++) {
                float a = av[j];
                float In = I + a;
                fires_s[t8 + j] = In;
                bool fire = (In >= 1.0f);
                wm_s[t8 + j] = fire ? (1.0f - I) : a;
                int Fc = (F < 1023) ? F : 1023;
                fp_s[Fc] = t8 + j;
                F += fire ? 1 : 0;
                I = fire ? (In - 1.0f) : In;
            }
        }
        F_sh = (F > 1024) ? 1024 : F;
        Fcount[b] = F_sh;
    }
    __syncthreads();
    const int F = F_sh;
    for (int t = tid; t < TT; t += 256) {
        out_peak[b * TT + t] = fires_s[t];
        w_main[b * TT + t]   = wm_s[t];
    }
    for (int s = tid; s < F; s += 256)
        fire_pos[b * 1024 + s] = fp_s[s];
}

// acoustic_embeds[b,s,:] = spill(prev fire) + sum over contiguous t-segment.
__global__ void cif_scatter(const float* __restrict__ hidden,
                            const float* __restrict__ alphas,
                            const float* __restrict__ w_main,
                            const int* __restrict__ fire_pos,
                            const int* __restrict__ Fcount,
                            float* __restrict__ out_emb) {
    const int s = blockIdx.x;
    const int b = blockIdx.y;
    const int tid = threadIdx.x;   // 0..127 -> d = 4*tid
    const int F = Fcount[b];

    float4 acc = make_float4(0.f, 0.f, 0.f, 0.f);
    if (s < F) {
        const int t_hi = fire_pos[b * 1024 + s];
        const int t_lo = (s > 0) ? fire_pos[b * 1024 + s - 1] : 0;
        for (int t = t_lo; t <= t_hi; t++) {
            float w;
            if (s > 0 && t == t_lo)
                w = alphas[b * TT + t] - w_main[b * TT + t];
            else
                w = w_main[b * TT + t];
            const float4 h = *(const float4*)(hidden + ((size_t)(b * TT + t)) * DD + 4 * tid);
            acc.x = fmaf(w, h.x, acc.x);
            acc.y = fmaf(w, h.y, acc.y);
            acc.z = fmaf(w, h.z, acc.z);
            acc.w = fmaf(w, h.w, acc.w);
        }
    }
    *(float4*)(out_emb + ((size_t)(b * LOUT + s)) * DD + 4 * tid) = acc;
}

extern "C" void kernel_launch(void* const* d_in, const int* in_sizes, int n_in,
                              void* d_out, int out_size, void* d_ws, size_t ws_size,
                              hipStream_t stream) {
    const float* hidden  = (const float*)d_in[0];
    const float* mask    = (const float*)d_in[1];
    const float* tll     = (const float*)d_in[2];
    const float* conv_w  = (const float*)d_in[3];
    const float* conv_b  = (const float*)d_in[4];
    const float* out_w   = (const float*)d_in[5];
    const float* out_b   = (const float*)d_in[6];

    float* out        = (float*)d_out;
    float* out_emb    = out;
    float* out_tn     = out + 4194304;
    float* out_alphas = out + 4194320;
    float* out_peak   = out + 4259856;

    char* ws = (char*)d_ws;
    _Float16* A_hi   = (_Float16*)(ws);
    _Float16* A_lo   = (_Float16*)(ws + 67108864);
    _Float16* B_hi   = (_Float16*)(ws + 134217728);
    _Float16* B_lo   = (_Float16*)(ws + 135790592);
    float* a_pre     = (float*)(ws + 137363456);
    float* w_main    = (float*)(ws + 137625600);
    int*   fire_pos  = (int*)(ws + 137887744);
    int*   Fcount    = (int*)(ws + 137953280);
    _Float16* zpage  = (_Float16*)(ws + 137953344);

    zero_ws<<<256, 256, 0, stream>>>(a_pre, zpage);
    split_hidden<<<16384, 256, 0, stream>>>(hidden, A_hi, A_lo);
    repack_wsplit<<<3072, 256, 0, stream>>>(conv_w, B_hi, B_lo);
    mfma_gemm<<<2048, 256, 0, stream>>>(ws, conv_b, out_w, a_pre);
    cif_scan<<<16, 256, 0, stream>>>(a_pre, mask, tll, out_b,
                                     out_tn, out_alphas, out_peak,
                                     w_main, fire_pos, Fcount);
    cif_scatter<<<dim3(512, 16), 128, 0, stream>>>(hidden, out_alphas, w_main,
                                                   fire_pos, Fcount, out_emb);
}

// Round 3
// 928.515 us; speedup vs baseline: 1.1041x; 1.1041x over previous
//
#include <hip/hip_runtime.h>
#include <math.h>

// Problem constants
#define BB 16
#define TT 4096
#define DD 512
#define LOUT 512

typedef __attribute__((ext_vector_type(8))) _Float16 half8;
typedef __attribute__((ext_vector_type(4))) float floatx4;

// ---------------------------------------------------------------------------
// Workspace layout (bytes):
//   A_hi    : _Float16[33554432] @ 0          (hidden hi split)
//   A_lo    : _Float16[33554432] @ 67108864   (hidden lo split)
//   B_hi    : _Float16[786432]   @ 134217728  (conv_w hi, [tap][c][i])
//   B_lo    : _Float16[786432]   @ 135790592
//   a_pre   : float[65536]       @ 137363456
//   w_main  : float[65536]       @ 137625600
//   fire_pos: int[16384]         @ 137887744
//   Fcount  : int[16]            @ 137953280
//   zpage16 : _Float16[512]      @ 137953344  (zero page, conv halo rows)
// ---------------------------------------------------------------------------

// Fused prep: split hidden -> f16 hi/lo, repack conv_w, zero a_pre + zpage.
__global__ void prep(const float* __restrict__ hidden,
                     const float* __restrict__ conv_w,
                     _Float16* __restrict__ A_hi,
                     _Float16* __restrict__ A_lo,
                     _Float16* __restrict__ B_hi,
                     _Float16* __restrict__ B_lo,
                     float* __restrict__ a_pre,
                     _Float16* __restrict__ zp) {
    int idx = blockIdx.x * 256 + threadIdx.x;    // 4194304 threads, 8 elems each
    const float4* src = (const float4*)(hidden + 8 * (size_t)idx);
    float4 v0 = src[0], v1 = src[1];
    float x[8] = {v0.x, v0.y, v0.z, v0.w, v1.x, v1.y, v1.z, v1.w};
    _Float16 hi[8], lo[8];
    #pragma unroll
    for (int j = 0; j < 8; j++) {
        hi[j] = (_Float16)x[j];
        lo[j] = (_Float16)(x[j] - (float)hi[j]);
    }
    *(half8*)(A_hi + 8 * (size_t)idx) = *(half8*)hi;
    *(half8*)(A_lo + 8 * (size_t)idx) = *(half8*)lo;

    if (idx < 786432) {                          // conv_w repack + split
        int tap = idx / 262144;
        int rem = idx - tap * 262144;
        int c = rem >> 9;
        int i = rem & 511;
        float v = conv_w[(c * 512 + i) * 3 + tap];
        _Float16 h = (_Float16)v;
        B_hi[idx] = h;
        B_lo[idx] = (_Float16)(v - (float)h);
    }
    if (idx < 65536) a_pre[idx] = 0.f;
    if (idx < 512)   zp[idx] = (_Float16)0.f;
}

#define GLL16(g, l) __builtin_amdgcn_global_load_lds( \
    (const __attribute__((address_space(1))) void*)(g), \
    (__attribute__((address_space(3))) void*)(l), 16, 0, 0)

// ---------------------------------------------------------------------------
// Split-f16 conv-GEMM, R1 structure (single LDS buffer, 2 barriers/kc) with:
//  - salt fix: chunk swizzle uses ((row>>1)&3) so 16 lanes spread over all 8
//    16B slots per 128B bank period -> 2-way aliasing (free) instead of 4-way
//  - A_lo/B_lo read direct global->VGPR (L1/L2-hot: 3x tap overlap, B shared
//    by all waves + 8 N-tiles per XCD) -> LDS = A_hi + B_hi only = 29696 B,
//    staging 29 units (was 58), LDS reads 24 KB/wave/kc (was 48)
//  - 3 blocks/CU (12 waves) for implicit cross-block phase overlap
// Block tile 256(M) x 64(N), 4 waves, wave tile 64x64 = 4x4 frags of 16x16x32.
// LDS: Ahi rows 0..271 @ 0 (17408 B), Bhi @ 17408 + tap*4096 (12288 B).
// ---------------------------------------------------------------------------
__launch_bounds__(256, 3)
__global__ void mfma_gemm(const char* __restrict__ wsb,
                          const float* __restrict__ conv_b,
                          const float* __restrict__ out_w,
                          float* __restrict__ a_pre) {
    __shared__ __align__(128) char lds[29696];

    const int tid  = threadIdx.x;
    const int w    = tid >> 6;            // wave 0..3 = M sub-tile
    const int lane = tid & 63;

    // XCD-chunked swizzle: all 8 N-tiles of an M-tile co-resident on one XCD.
    const int bid = blockIdx.x;
    const int swz = (bid & 7) * 256 + (bid >> 3);
    const int nt  = swz & 7;
    const int mt  = swz >> 3;
    const int b   = mt >> 4;
    const int t0  = (mt & 15) << 8;
    const int c0  = nt << 6;

    const int srow = lane >> 2;           // staging: lane -> row in unit
    const int schk = lane & 3;

    // ---- staging descriptors: 29 GLL16 units (Ahi u0..16, Bhi tap x 4) ----
    int sgoff[8], sloff[8];
    #pragma unroll
    for (int j = 0; j < 8; j++) {
        const int g = w + 4 * j;
        int so = 137953344, lo = 0;
        if (g < 29) {
            if (g < 17) {                              // Ahi unit u = g
                const int r  = 16 * g + srow;          // LDS row 0..271
                const int t  = t0 - 1 + r;
                const int sw = (schk ^ ((r >> 1) & 3)) << 4;  // pre-swizzled
                so = (t >= 0 && t < TT) ? (b * TT + t) * 1024 + sw
                                        : 137953344 + sw;
                lo = g * 1024;
            } else {                                   // Bhi units
                const int h  = g - 17;
                const int tp = h >> 2;
                const int u  = h & 3;
                const int r  = 16 * u + srow;
                const int sw = (schk ^ ((r >> 1) & 3)) << 4;
                so = 134217728 + tp * 524288 + (c0 + r) * 1024 + sw;
                lo = 17408 + tp * 4096 + u * 1024;
            }
        }
        sgoff[j] = so;
        sloff[j] = lo;
    }

    // ---- LDS frag read offsets (swizzled with matching salt) ----
    int aoff[12], boff[4];
    #pragma unroll
    for (int tap = 0; tap < 3; tap++)
        #pragma unroll
        for (int i = 0; i < 4; i++) {
            const int ra = 64 * w + 16 * i + (lane & 15) + tap;
            aoff[tap * 4 + i] = ra * 64 + (((lane >> 4) ^ ((ra >> 1) & 3)) << 4);
        }
    #pragma unroll
    for (int i = 0; i < 4; i++) {
        const int rb = 16 * i + (lane & 15);
        boff[i] = rb * 64 + (((lane >> 4) ^ ((rb >> 1) & 3)) << 4);
    }

    // ---- direct-global lo-operand bases ----
    const int chb   = (lane >> 4) << 4;                // logical chunk bytes
    const int tb    = t0 - 1 + 64 * w + (lane & 15);   // A_lo row base
    const int bTT   = b * TT;
    const int bbase = 135790592 + (c0 + (lane & 15)) * 1024 + chb;

    floatx4 acc[4][4];
    #pragma unroll
    for (int mi = 0; mi < 4; mi++)
        #pragma unroll
        for (int ni = 0; ni < 4; ni++)
            acc[mi][ni] = (floatx4)(0.f);

    // epilogue constants: col n = c0 + 16*ni + (lane&15)
    float u_n[4], cb_n[4];
    #pragma unroll
    for (int ni = 0; ni < 4; ni++) {
        int n = c0 + 16 * ni + (lane & 15);
        u_n[ni]  = out_w[n];
        cb_n[ni] = conv_b[n];
    }

    for (int kc = 0; kc < 16; kc++) {
        const int kb = kc << 6;           // 32 f16 = 64 B per k-chunk

        // ---- stage hi operands (29 units across 4 waves) ----
        #pragma unroll
        for (int j = 0; j < 8; j++)
            if (w + 4 * j < 29)
                GLL16(wsb + (size_t)(sgoff[j] + kb), lds + sloff[j]);
        __syncthreads();

        // ---- compute: 3 taps x (Ahi*Bhi + Alo*Bhi + Ahi*Blo) ----
        #pragma unroll
        for (int tap = 0; tap < 3; tap++) {
            half8 ah[4], bh[4], al[4], bl[4];
            #pragma unroll
            for (int i = 0; i < 4; i++) {
                ah[i] = *(const half8*)(lds + aoff[tap * 4 + i]);
                bh[i] = *(const half8*)(lds + 17408 + tap * 4096 + boff[i]);
                const int vt = tb + 16 * i + tap;
                const int ga = ((unsigned)vt < (unsigned)TT)
                    ? 67108864 + (bTT + vt) * 1024 + chb
                    : 137953344 + chb;
                al[i] = *(const half8*)(wsb + (size_t)(ga + kb));
                bl[i] = *(const half8*)(wsb + (size_t)(bbase + tap * 524288
                                                       + i * 16384 + kb));
            }
            __builtin_amdgcn_s_setprio(1);
            #pragma unroll
            for (int mi = 0; mi < 4; mi++)
                #pragma unroll
                for (int ni = 0; ni < 4; ni++)
                    acc[mi][ni] = __builtin_amdgcn_mfma_f32_16x16x32_f16(
                        ah[mi], bh[ni], acc[mi][ni], 0, 0, 0);
            #pragma unroll
            for (int mi = 0; mi < 4; mi++)
                #pragma unroll
                for (int ni = 0; ni < 4; ni++)
                    acc[mi][ni] = __builtin_amdgcn_mfma_f32_16x16x32_f16(
                        al[mi], bh[ni], acc[mi][ni], 0, 0, 0);
            #pragma unroll
            for (int mi = 0; mi < 4; mi++)
                #pragma unroll
                for (int ni = 0; ni < 4; ni++)
                    acc[mi][ni] = __builtin_amdgcn_mfma_f32_16x16x32_f16(
                        ah[mi], bl[ni], acc[mi][ni], 0, 0, 0);
            __builtin_amdgcn_s_setprio(0);
        }
        __syncthreads();
    }

    // epilogue: s[mi][reg] = sum_ni relu(acc + cb)*u ; reduce over lane&15 ; atomic
    float s[4][4];
    #pragma unroll
    for (int mi = 0; mi < 4; mi++)
        #pragma unroll
        for (int rg = 0; rg < 4; rg++) {
            float t = 0.f;
            #pragma unroll
            for (int ni = 0; ni < 4; ni++) {
                float y = acc[mi][ni][rg] + cb_n[ni];
                y = y > 0.f ? y : 0.f;
                t = fmaf(y, u_n[ni], t);
            }
            s[mi][rg] = t;
        }
    #pragma unroll
    for (int mi = 0; mi < 4; mi++)
        #pragma unroll
        for (int rg = 0; rg < 4; rg++) {
            #pragma unroll
            for (int off = 1; off < 16; off <<= 1)
                s[mi][rg] += __shfl_xor(s[mi][rg], off);
        }
    if ((lane & 15) == 0) {
        const int q = lane >> 4;
        #pragma unroll
        for (int mi = 0; mi < 4; mi++)
            #pragma unroll
            for (int rg = 0; rg < 4; rg++) {
                int m = 64 * w + 16 * mi + 4 * q + rg;
                atomicAdd(&a_pre[b * TT + t0 + m], s[mi][rg]);
            }
    }
}

// Per-batch: sigmoid -> token_num -> rescale -> sequential CIF scan (pipelined).
__global__ void cif_scan(const float* __restrict__ a_pre,
                         const float* __restrict__ mask,
                         const float* __restrict__ tll,
                         const float* __restrict__ out_bias,
                         float* __restrict__ out_tn,
                         float* __restrict__ out_alphas,
                         float* __restrict__ out_peak,
                         float* __restrict__ w_main,
                         int* __restrict__ fire_pos,
                         int* __restrict__ Fcount) {
    __shared__ float alpha_s[TT];
    __shared__ float wm_s[TT];
    __shared__ float fires_s[TT];
    __shared__ int   fp_s[1024];
    __shared__ double red[256];
    __shared__ float ratio_s;
    __shared__ int   F_sh;

    const int b = blockIdx.x;
    const int tid = threadIdx.x;
    const float ob = out_bias[0];

    double lsum = 0.0;
    for (int t = tid; t < TT; t += 256) {
        float a = a_pre[b * TT + t] + ob;
        float e = expf(-fabsf(a));
        float sg = (a >= 0.f) ? (1.f / (1.f + e)) : (e / (1.f + e));
        float af = sg;
        af = af > 0.f ? af : 0.f;
        af = af * mask[b * TT + t];
        alpha_s[t] = af;
        lsum += (double)af;
    }
    red[tid] = lsum;
    __syncthreads();
    for (int off = 128; off > 0; off >>= 1) {
        if (tid < off) red[tid] += red[tid + off];
        __syncthreads();
    }
    if (tid == 0) {
        float tn = (float)red[0];
        out_tn[b] = tn;
        ratio_s = tll[b] / tn;
    }
    __syncthreads();
    const float ratio = ratio_s;
    for (int t = tid; t < TT; t += 256) {
        float a = alpha_s[t] * ratio;
        alpha_s[t] = a;
        out_alphas[b * TT + t] = a;
    }
    __syncthreads();

    if (tid == 0) {
        float I = 0.f;
        int F = 0;
        float4 n0 = *(const float4*)&alpha_s[0];
        float4 n1 = *(const float4*)&alpha_s[4];
        for (int t8 = 0; t8 < TT; t8 += 8) {
            float av[8];
            *(float4*)&av[0] = n0;
            *(float4*)&av[4] = n1;
            if (t8 + 8 < TT) {
                n0 = *(const float4*)&alpha_s[t8 + 8];
                n1 = *(const float4*)&alpha_s[t8 + 12];
            }
            #pragma unroll
            for (int j = 0; j < 8; j++) {
                float a = av[j];
                float In = I + a;
                fires_s[t8 + j] = In;
                bool fire = (In >= 1.0f);
                wm_s[t8 + j] = fire ? (1.0f - I) : a;
                int Fc = (F < 1023) ? F : 1023;
                fp_s[Fc] = t8 + j;
                F += fire ? 1 : 0;
                I = fire ? (In - 1.0f) : In;
            }
        }
        F_sh = (F > 1024) ? 1024 : F;
        Fcount[b] = F_sh;
    }
    __syncthreads();
    const int F = F_sh;
    for (int t = tid; t < TT; t += 256) {
        out_peak[b * TT + t] = fires_s[t];
        w_main[b * TT + t]   = wm_s[t];
    }
    for (int s = tid; s < F; s += 256)
        fire_pos[b * 1024 + s] = fp_s[s];
}

// acoustic_embeds[b,s,:] = spill(prev fire) + sum over contiguous t-segment.
__global__ void cif_scatter(const float* __restrict__ hidden,
                            const float* __restrict__ alphas,
                            const float* __restrict__ w_main,
                            const int* __restrict__ fire_pos,
                            const int* __restrict__ Fcount,
                            float* __restrict__ out_emb) {
    const int s = blockIdx.x;
    const int b = blockIdx.y;
    const int tid = threadIdx.x;   // 0..127 -> d = 4*tid
    const int F = Fcount[b];

    float4 acc = make_float4(0.f, 0.f, 0.f, 0.f);
    if (s < F) {
        const int t_hi = fire_pos[b * 1024 + s];
        const int t_lo = (s > 0) ? fire_pos[b * 1024 + s - 1] : 0;
        for (int t = t_lo; t <= t_hi; t++) {
            float w;
            if (s > 0 && t == t_lo)
                w = alphas[b * TT + t] - w_main[b * TT + t];
            else
                w = w_main[b * TT + t];
            const float4 h = *(const float4*)(hidden + ((size_t)(b * TT + t)) * DD + 4 * tid);
            acc.x = fmaf(w, h.x, acc.x);
            acc.y = fmaf(w, h.y, acc.y);
            acc.z = fmaf(w, h.z, acc.z);
            acc.w = fmaf(w, h.w, acc.w);
        }
    }
    *(float4*)(out_emb + ((size_t)(b * LOUT + s)) * DD + 4 * tid) = acc;
}

extern "C" void kernel_launch(void* const* d_in, const int* in_sizes, int n_in,
                              void* d_out, int out_size, void* d_ws, size_t ws_size,
                              hipStream_t stream) {
    const float* hidden  = (const float*)d_in[0];
    const float* mask    = (const float*)d_in[1];
    const float* tll     = (const float*)d_in[2];
    const float* conv_w  = (const float*)d_in[3];
    const float* conv_b  = (const float*)d_in[4];
    const float* out_w   = (const float*)d_in[5];
    const float* out_b   = (const float*)d_in[6];

    float* out        = (float*)d_out;
    float* out_emb    = out;
    float* out_tn     = out + 4194304;
    float* out_alphas = out + 4194320;
    float* out_peak   = out + 4259856;

    char* ws = (char*)d_ws;
    _Float16* A_hi   = (_Float16*)(ws);
    _Float16* A_lo   = (_Float16*)(ws + 67108864);
    _Float16* B_hi   = (_Float16*)(ws + 134217728);
    _Float16* B_lo   = (_Float16*)(ws + 135790592);
    float* a_pre     = (float*)(ws + 137363456);
    float* w_main    = (float*)(ws + 137625600);
    int*   fire_pos  = (int*)(ws + 137887744);
    int*   Fcount    = (int*)(ws + 137953280);
    _Float16* zpage  = (_Float16*)(ws + 137953344);

    prep<<<16384, 256, 0, stream>>>(hidden, conv_w, A_hi, A_lo, B_hi, B_lo,
                                    a_pre, zpage);
    mfma_gemm<<<2048, 256, 0, stream>>>(ws, conv_b, out_w, a_pre);
    cif_scan<<<16, 256, 0, stream>>>(a_pre, mask, tll, out_b,
                                     out_tn, out_alphas, out_peak,
                                     w_main, fire_pos, Fcount);
    cif_scatter<<<dim3(512, 16), 128, 0, stream>>>(hidden, out_alphas, w_main,
                                                   fire_pos, Fcount, out_emb);
}

// Round 4
// 778.449 us; speedup vs baseline: 1.3169x; 1.1928x over previous
//
#include <hip/hip_runtime.h>
#include <math.h>

// Problem constants
#define BB 16
#define TT 4096
#define DD 512
#define LOUT 512

typedef __attribute__((ext_vector_type(8))) _Float16 half8;
typedef __attribute__((ext_vector_type(16))) float floatx16;

// ---------------------------------------------------------------------------
// Workspace layout (bytes):
//   A_hi    : _Float16[33554432] @ 0          (hidden hi split)
//   A_lo    : _Float16[33554432] @ 67108864   (hidden lo split)
//   B_hi    : _Float16[786432]   @ 134217728  (conv_w hi, [tap][c][i])
//   B_lo    : _Float16[786432]   @ 135790592
//   a_pre   : float[65536]       @ 137363456
//   w_main  : float[65536]       @ 137625600
//   fire_pos: int[16384]         @ 137887744
//   Fcount  : int[16]            @ 137953280
//   zpage16 : _Float16[512]      @ 137953344  (zero page, conv halo rows)
// ---------------------------------------------------------------------------

// Fused prep: split hidden -> f16 hi/lo, repack conv_w, zero a_pre + zpage.
__global__ void prep(const float* __restrict__ hidden,
                     const float* __restrict__ conv_w,
                     _Float16* __restrict__ A_hi,
                     _Float16* __restrict__ A_lo,
                     _Float16* __restrict__ B_hi,
                     _Float16* __restrict__ B_lo,
                     float* __restrict__ a_pre,
                     _Float16* __restrict__ zp) {
    int idx = blockIdx.x * 256 + threadIdx.x;    // 4194304 threads, 8 elems each
    const float4* src = (const float4*)(hidden + 8 * (size_t)idx);
    float4 v0 = src[0], v1 = src[1];
    float x[8] = {v0.x, v0.y, v0.z, v0.w, v1.x, v1.y, v1.z, v1.w};
    _Float16 hi[8], lo[8];
    #pragma unroll
    for (int j = 0; j < 8; j++) {
        hi[j] = (_Float16)x[j];
        lo[j] = (_Float16)(x[j] - (float)hi[j]);
    }
    *(half8*)(A_hi + 8 * (size_t)idx) = *(half8*)hi;
    *(half8*)(A_lo + 8 * (size_t)idx) = *(half8*)lo;

    if (idx < 786432) {                          // conv_w repack + split
        int tap = idx / 262144;
        int rem = idx - tap * 262144;
        int c = rem >> 9;
        int i = rem & 511;
        float v = conv_w[(c * 512 + i) * 3 + tap];
        _Float16 h = (_Float16)v;
        B_hi[idx] = h;
        B_lo[idx] = (_Float16)(v - (float)h);
    }
    if (idx < 65536) a_pre[idx] = 0.f;
    if (idx < 512)   zp[idx] = (_Float16)0.f;
}

#define GLL16(g, l) __builtin_amdgcn_global_load_lds( \
    (const __attribute__((address_space(1))) void*)(g), \
    (__attribute__((address_space(3))) void*)(l), 16, 0, 0)

// ---------------------------------------------------------------------------
// Split-f16 conv-GEMM, R1 structure (ALL operands staged to LDS, single
// buffer, 2 barriers/kc, 2 blocks/CU) with:
//  - salt ((row>>1)&3) chunk-XOR swizzle (R3-proven: bank conflicts = 0)
//  - MFMA shape 32x32x16 (2382+ TF ceiling vs 2075): wave tile 64x64 =
//    2x2 frags of 32x32, 24 mfma/tap, 72/kc/wave. Same LDS traffic,
//    same acc VGPR count as the 16x16x32 version.
// Block tile 256(M) x 64(N), 4 waves.
// LDS 59392 B: Ahi @0 (272 rows x 64B), Alo @17408,
//              Bhi @34816+tap*4096, Blo @47104+tap*4096.
// Frag layouts (gfx950, documented+verified lineage):
//   A/B operand: row/col = lane&31, k = (lane>>5)*8 + j  (8 contiguous f16)
//   C/D: col = lane&31, row = (reg&3) + 8*(reg>>2) + 4*(lane>>5)
// ---------------------------------------------------------------------------
__launch_bounds__(256, 2)
__global__ void mfma_gemm(const char* __restrict__ wsb,
                          const float* __restrict__ conv_b,
                          const float* __restrict__ out_w,
                          float* __restrict__ a_pre) {
    __shared__ __align__(128) char lds[59392];

    const int tid  = threadIdx.x;
    const int w    = tid >> 6;            // wave 0..3 = M sub-tile
    const int lane = tid & 63;

    // XCD-chunked swizzle: all 8 N-tiles of an M-tile co-resident on one XCD.
    const int bid = blockIdx.x;
    const int swz = (bid & 7) * 256 + (bid >> 3);
    const int nt  = swz & 7;
    const int mt  = swz >> 3;
    const int b   = mt >> 4;
    const int t0  = (mt & 15) << 8;
    const int c0  = nt << 6;

    const int srow = lane >> 2;           // staging: lane -> row in unit
    const int schk = lane & 3;

    // ---- staging descriptors: 58 GLL16 units ----
    // g<17: Ahi, 17..33: Alo, 34..57: B (dt x tap x u). Unit g -> wave g&3.
    int sgoff[15], sloff[15];
    #pragma unroll
    for (int j = 0; j < 15; j++) {
        const int g = w + 4 * j;
        int so = 137953344, lo = 0;
        if (g < 58) {
            if (g < 34) {                              // A units
                const int dt = (g >= 17);              // 0=hi 1=lo
                const int u  = dt ? g - 17 : g;
                const int r  = 16 * u + srow;          // LDS row 0..271
                const int t  = t0 - 1 + r;
                const int sw = (schk ^ ((r >> 1) & 3)) << 4;  // pre-swizzled
                so = (t >= 0 && t < TT) ? (dt ? 67108864 : 0)
                                          + (b * TT + t) * 1024 + sw
                                        : 137953344 + sw;
                lo = dt * 17408 + u * 1024;
            } else {                                   // B units
                const int h  = g - 34;
                const int dt = h / 12;
                const int rm = h % 12;
                const int tp = rm >> 2;
                const int u  = rm & 3;
                const int r  = 16 * u + srow;
                const int sw = (schk ^ ((r >> 1) & 3)) << 4;
                so = (dt ? 135790592 : 134217728) + tp * 524288
                     + (c0 + r) * 1024 + sw;
                lo = 34816 + dt * 12288 + tp * 4096 + u * 1024;
            }
        }
        sgoff[j] = so;
        sloff[j] = lo;
    }

    // ---- LDS frag read offsets (salt-matched swizzle) ----
    // A: aoff[tap][mi][ks]; row ra = 64w + 32mi + (lane&31) + tap
    // chunk = 2*ks + (lane>>5), phys = chunk ^ ((ra>>1)&3)
    int aoff[3][2][2];
    #pragma unroll
    for (int tap = 0; tap < 3; tap++)
        #pragma unroll
        for (int mi = 0; mi < 2; mi++)
            #pragma unroll
            for (int ks = 0; ks < 2; ks++) {
                const int ra = 64 * w + 32 * mi + (lane & 31) + tap;
                aoff[tap][mi][ks] = ra * 64
                    + (((2 * ks + (lane >> 5)) ^ ((ra >> 1) & 3)) << 4);
            }
    // B: boff[ni][ks]; row rb = 32ni + (lane&31)
    int boff[2][2];
    #pragma unroll
    for (int ni = 0; ni < 2; ni++)
        #pragma unroll
        for (int ks = 0; ks < 2; ks++) {
            const int rb = 32 * ni + (lane & 31);
            boff[ni][ks] = rb * 64
                + (((2 * ks + (lane >> 5)) ^ ((rb >> 1) & 3)) << 4);
        }

    floatx16 acc[2][2];
    #pragma unroll
    for (int mi = 0; mi < 2; mi++)
        #pragma unroll
        for (int ni = 0; ni < 2; ni++)
            acc[mi][ni] = (floatx16)(0.f);

    // epilogue constants: col n = c0 + 32*ni + (lane&31)
    float u2[2], cb2[2];
    #pragma unroll
    for (int ni = 0; ni < 2; ni++) {
        int n = c0 + 32 * ni + (lane & 31);
        u2[ni]  = out_w[n];
        cb2[ni] = conv_b[n];
    }

    for (int kc = 0; kc < 16; kc++) {
        const int kb = kc << 6;           // 32 f16 = 64 B per k-chunk

        // ---- stage all operands (58 units across 4 waves) ----
        #pragma unroll
        for (int j = 0; j < 15; j++)
            if (w + 4 * j < 58)
                GLL16(wsb + (size_t)(sgoff[j] + kb), lds + sloff[j]);
        __syncthreads();

        // ---- compute: 3 taps x (Ahi*Bhi + Alo*Bhi + Ahi*Blo) ----
        #pragma unroll
        for (int tap = 0; tap < 3; tap++) {
            half8 ah[2][2], al[2][2], bh[2][2], bl[2][2];
            #pragma unroll
            for (int mi = 0; mi < 2; mi++)
                #pragma unroll
                for (int ks = 0; ks < 2; ks++) {
                    ah[mi][ks] = *(const half8*)(lds + aoff[tap][mi][ks]);
                    al[mi][ks] = *(const half8*)(lds + 17408 + aoff[tap][mi][ks]);
                }
            #pragma unroll
            for (int ni = 0; ni < 2; ni++)
                #pragma unroll
                for (int ks = 0; ks < 2; ks++) {
                    bh[ni][ks] = *(const half8*)(lds + 34816 + tap * 4096
                                                 + boff[ni][ks]);
                    bl[ni][ks] = *(const half8*)(lds + 47104 + tap * 4096
                                                 + boff[ni][ks]);
                }
            __builtin_amdgcn_s_setprio(1);
            #pragma unroll
            for (int ks = 0; ks < 2; ks++)
                #pragma unroll
                for (int mi = 0; mi < 2; mi++)
                    #pragma unroll
                    for (int ni = 0; ni < 2; ni++)
                        acc[mi][ni] = __builtin_amdgcn_mfma_f32_32x32x16_f16(
                            ah[mi][ks], bh[ni][ks], acc[mi][ni], 0, 0, 0);
            #pragma unroll
            for (int ks = 0; ks < 2; ks++)
                #pragma unroll
                for (int mi = 0; mi < 2; mi++)
                    #pragma unroll
                    for (int ni = 0; ni < 2; ni++)
                        acc[mi][ni] = __builtin_amdgcn_mfma_f32_32x32x16_f16(
                            al[mi][ks], bh[ni][ks], acc[mi][ni], 0, 0, 0);
            #pragma unroll
            for (int ks = 0; ks < 2; ks++)
                #pragma unroll
                for (int mi = 0; mi < 2; mi++)
                    #pragma unroll
                    for (int ni = 0; ni < 2; ni++)
                        acc[mi][ni] = __builtin_amdgcn_mfma_f32_32x32x16_f16(
                            ah[mi][ks], bl[ni][ks], acc[mi][ni], 0, 0, 0);
            __builtin_amdgcn_s_setprio(0);
        }
        __syncthreads();
    }

    // ---- epilogue ----
    // lane holds col n=32ni+(lane&31); reg r -> row (r&3)+8*(r>>2)+4*(lane>>5)
    // s[mi][r] = sum_ni relu(acc+cb)*u ; reduce over lane&31 ; 2 writer lanes
    float s[2][16];
    #pragma unroll
    for (int mi = 0; mi < 2; mi++)
        #pragma unroll
        for (int r = 0; r < 16; r++) {
            float t = 0.f;
            #pragma unroll
            for (int ni = 0; ni < 2; ni++) {
                float y = acc[mi][ni][r] + cb2[ni];
                y = y > 0.f ? y : 0.f;
                t = fmaf(y, u2[ni], t);
            }
            s[mi][r] = t;
        }
    #pragma unroll
    for (int mi = 0; mi < 2; mi++)
        #pragma unroll
        for (int r = 0; r < 16; r++) {
            #pragma unroll
            for (int off = 1; off < 32; off <<= 1)
                s[mi][r] += __shfl_xor(s[mi][r], off);
        }
    if ((lane & 31) == 0) {
        const int q = lane >> 5;
        #pragma unroll
        for (int mi = 0; mi < 2; mi++)
            #pragma unroll
            for (int r = 0; r < 16; r++) {
                int m = 64 * w + 32 * mi + 4 * q + (r & 3) + 8 * (r >> 2);
                atomicAdd(&a_pre[b * TT + t0 + m], s[mi][r]);
            }
    }
}

// Per-batch: sigmoid -> token_num -> rescale -> sequential CIF scan (pipelined).
__global__ void cif_scan(const float* __restrict__ a_pre,
                         const float* __restrict__ mask,
                         const float* __restrict__ tll,
                         const float* __restrict__ out_bias,
                         float* __restrict__ out_tn,
                         float* __restrict__ out_alphas,
                         float* __restrict__ out_peak,
                         float* __restrict__ w_main,
                         int* __restrict__ fire_pos,
                         int* __restrict__ Fcount) {
    __shared__ float alpha_s[TT];
    __shared__ float wm_s[TT];
    __shared__ float fires_s[TT];
    __shared__ int   fp_s[1024];
    __shared__ double red[256];
    __shared__ float ratio_s;
    __shared__ int   F_sh;

    const int b = blockIdx.x;
    const int tid = threadIdx.x;
    const float ob = out_bias[0];

    double lsum = 0.0;
    for (int t = tid; t < TT; t += 256) {
        float a = a_pre[b * TT + t] + ob;
        float e = expf(-fabsf(a));
        float sg = (a >= 0.f) ? (1.f / (1.f + e)) : (e / (1.f + e));
        float af = sg;
        af = af > 0.f ? af : 0.f;
        af = af * mask[b * TT + t];
        alpha_s[t] = af;
        lsum += (double)af;
    }
    red[tid] = lsum;
    __syncthreads();
    for (int off = 128; off > 0; off >>= 1) {
        if (tid < off) red[tid] += red[tid + off];
        __syncthreads();
    }
    if (tid == 0) {
        float tn = (float)red[0];
        out_tn[b] = tn;
        ratio_s = tll[b] / tn;
    }
    __syncthreads();
    const float ratio = ratio_s;
    for (int t = tid; t < TT; t += 256) {
        float a = alpha_s[t] * ratio;
        alpha_s[t] = a;
        out_alphas[b * TT + t] = a;
    }
    __syncthreads();

    if (tid == 0) {
        float I = 0.f;
        int F = 0;
        float4 n0 = *(const float4*)&alpha_s[0];
        float4 n1 = *(const float4*)&alpha_s[4];
        for (int t8 = 0; t8 < TT; t8 += 8) {
            float av[8];
            *(float4*)&av[0] = n0;
            *(float4*)&av[4] = n1;
            if (t8 + 8 < TT) {
                n0 = *(const float4*)&alpha_s[t8 + 8];
                n1 = *(const float4*)&alpha_s[t8 + 12];
            }
            #pragma unroll
            for (int j = 0; j < 8; j++) {
                float a = av[j];
                float In = I + a;
                fires_s[t8 + j] = In;
                bool fire = (In >= 1.0f);
                wm_s[t8 + j] = fire ? (1.0f - I) : a;
                int Fc = (F < 1023) ? F : 1023;
                fp_s[Fc] = t8 + j;
                F += fire ? 1 : 0;
                I = fire ? (In - 1.0f) : In;
            }
        }
        F_sh = (F > 1024) ? 1024 : F;
        Fcount[b] = F_sh;
    }
    __syncthreads();
    const int F = F_sh;
    for (int t = tid; t < TT; t += 256) {
        out_peak[b * TT + t] = fires_s[t];
        w_main[b * TT + t]   = wm_s[t];
    }
    for (int s = tid; s < F; s += 256)
        fire_pos[b * 1024 + s] = fp_s[s];
}

// acoustic_embeds[b,s,:] = spill(prev fire) + sum over contiguous t-segment.
__global__ void cif_scatter(const float* __restrict__ hidden,
                            const float* __restrict__ alphas,
                            const float* __restrict__ w_main,
                            const int* __restrict__ fire_pos,
                            const int* __restrict__ Fcount,
                            float* __restrict__ out_emb) {
    const int s = blockIdx.x;
    const int b = blockIdx.y;
    const int tid = threadIdx.x;   // 0..127 -> d = 4*tid
    const int F = Fcount[b];

    float4 acc = make_float4(0.f, 0.f, 0.f, 0.f);
    if (s < F) {
        const int t_hi = fire_pos[b * 1024 + s];
        const int t_lo = (s > 0) ? fire_pos[b * 1024 + s - 1] : 0;
        for (int t = t_lo; t <= t_hi; t++) {
            float w;
            if (s > 0 && t == t_lo)
                w = alphas[b * TT + t] - w_main[b * TT + t];
            else
                w = w_main[b * TT + t];
            const float4 h = *(const float4*)(hidden + ((size_t)(b * TT + t)) * DD + 4 * tid);
            acc.x = fmaf(w, h.x, acc.x);
            acc.y = fmaf(w, h.y, acc.y);
            acc.z = fmaf(w, h.z, acc.z);
            acc.w = fmaf(w, h.w, acc.w);
        }
    }
    *(float4*)(out_emb + ((size_t)(b * LOUT + s)) * DD + 4 * tid) = acc;
}

extern "C" void kernel_launch(void* const* d_in, const int* in_sizes, int n_in,
                              void* d_out, int out_size, void* d_ws, size_t ws_size,
                              hipStream_t stream) {
    const float* hidden  = (const float*)d_in[0];
    const float* mask    = (const float*)d_in[1];
    const float* tll     = (const float*)d_in[2];
    const float* conv_w  = (const float*)d_in[3];
    const float* conv_b  = (const float*)d_in[4];
    const float* out_w   = (const float*)d_in[5];
    const float* out_b   = (const float*)d_in[6];

    float* out        = (float*)d_out;
    float* out_emb    = out;
    float* out_tn     = out + 4194304;
    float* out_alphas = out + 4194320;
    float* out_peak   = out + 4259856;

    char* ws = (char*)d_ws;
    _Float16* A_hi   = (_Float16*)(ws);
    _Float16* A_lo   = (_Float16*)(ws + 67108864);
    _Float16* B_hi   = (_Float16*)(ws + 134217728);
    _Float16* B_lo   = (_Float16*)(ws + 135790592);
    float* a_pre     = (float*)(ws + 137363456);
    float* w_main    = (float*)(ws + 137625600);
    int*   fire_pos  = (int*)(ws + 137887744);
    int*   Fcount    = (int*)(ws + 137953280);
    _Float16* zpage  = (_Float16*)(ws + 137953344);

    prep<<<16384, 256, 0, stream>>>(hidden, conv_w, A_hi, A_lo, B_hi, B_lo,
                                    a_pre, zpage);
    mfma_gemm<<<2048, 256, 0, stream>>>(ws, conv_b, out_w, a_pre);
    cif_scan<<<16, 256, 0, stream>>>(a_pre, mask, tll, out_b,
                                     out_tn, out_alphas, out_peak,
                                     w_main, fire_pos, Fcount);
    cif_scatter<<<dim3(512, 16), 128, 0, stream>>>(hidden, out_alphas, w_main,
                                                   fire_pos, Fcount, out_emb);
}

// Round 5
// 718.883 us; speedup vs baseline: 1.4261x; 1.0829x over previous
//
#include <hip/hip_runtime.h>
#include <math.h>

// Problem constants
#define BB 16
#define TT 4096
#define DD 512
#define LOUT 512

typedef __attribute__((ext_vector_type(8))) _Float16 half8;
typedef __attribute__((ext_vector_type(4))) float floatx4;

// ---------------------------------------------------------------------------
// Workspace layout (bytes):
//   A_hi    : _Float16[33554432] @ 0          (hidden hi split)
//   A_lo    : _Float16[33554432] @ 67108864   (hidden lo split)
//   B_hi    : _Float16[786432]   @ 134217728  (conv_w hi, [tap][c][i])
//   B_lo    : _Float16[786432]   @ 135790592
//   a_pre   : float[65536]       @ 137363456
//   w_main  : float[65536]       @ 137625600
//   fire_pos: int[16384]         @ 137887744
//   Fcount  : int[16]            @ 137953280
//   zpage16 : _Float16[512]      @ 137953344  (zero page, conv halo rows)
// ---------------------------------------------------------------------------

// Fused prep: split hidden -> f16 hi/lo, repack conv_w, zero a_pre + zpage.
__global__ void prep(const float* __restrict__ hidden,
                     const float* __restrict__ conv_w,
                     _Float16* __restrict__ A_hi,
                     _Float16* __restrict__ A_lo,
                     _Float16* __restrict__ B_hi,
                     _Float16* __restrict__ B_lo,
                     float* __restrict__ a_pre,
                     _Float16* __restrict__ zp) {
    int idx = blockIdx.x * 256 + threadIdx.x;    // 4194304 threads, 8 elems each
    const float4* src = (const float4*)(hidden + 8 * (size_t)idx);
    float4 v0 = src[0], v1 = src[1];
    float x[8] = {v0.x, v0.y, v0.z, v0.w, v1.x, v1.y, v1.z, v1.w};
    _Float16 hi[8], lo[8];
    #pragma unroll
    for (int j = 0; j < 8; j++) {
        hi[j] = (_Float16)x[j];
        lo[j] = (_Float16)(x[j] - (float)hi[j]);
    }
    *(half8*)(A_hi + 8 * (size_t)idx) = *(half8*)hi;
    *(half8*)(A_lo + 8 * (size_t)idx) = *(half8*)lo;

    if (idx < 786432) {                          // conv_w repack + split
        int tap = idx / 262144;
        int rem = idx - tap * 262144;
        int c = rem >> 9;
        int i = rem & 511;
        float v = conv_w[(c * 512 + i) * 3 + tap];
        _Float16 h = (_Float16)v;
        B_hi[idx] = h;
        B_lo[idx] = (_Float16)(v - (float)h);
    }
    if (idx < 65536) a_pre[idx] = 0.f;
    if (idx < 512)   zp[idx] = (_Float16)0.f;
}

#define GLL16(g, l) __builtin_amdgcn_global_load_lds( \
    (const __attribute__((address_space(1))) void*)(g), \
    (__attribute__((address_space(3))) void*)(l), 16, 0, 0)

// ---------------------------------------------------------------------------
// Split-f16 conv-GEMM. R1 structure exactly (verified 267 us):
//   - ALL operands staged to LDS via 58 GLL16 units, single 59392 B buffer,
//     2 barriers per k-chunk, 2 blocks/CU, 16x16x32 MFMA, 4x4 frags/wave.
// Single change vs R1: swizzle salt (r&3) -> ((r>>1)&3) on BOTH the staging
// global-source pre-swizzle and the frag-read offsets. R3 proved this exact
// read pattern (chunk = lane>>4 spanning 4 slots, rows spanning 16, salt
// (r>>1)&3) measures ZERO bank conflicts; R1's (r&3) salt correlated row
// parity with slot class (4 of 8 classes used -> 4-way conflict, 2.52e7).
// Block tile 256(M) x 64(N), 4 waves, wave tile 64x64.
// LDS: Ahi @0 (272 rows x 64B), Alo @17408, Bhi @34816+tap*4096,
//      Blo @47104+tap*4096.
// ---------------------------------------------------------------------------
__launch_bounds__(256, 2)
__global__ void mfma_gemm(const char* __restrict__ wsb,
                          const float* __restrict__ conv_b,
                          const float* __restrict__ out_w,
                          float* __restrict__ a_pre) {
    __shared__ __align__(128) char lds[59392];

    const int tid  = threadIdx.x;
    const int w    = tid >> 6;            // wave 0..3 = M sub-tile
    const int lane = tid & 63;

    // XCD-chunked swizzle: all 8 N-tiles of an M-tile co-resident on one XCD.
    const int bid = blockIdx.x;
    const int swz = (bid & 7) * 256 + (bid >> 3);
    const int nt  = swz & 7;
    const int mt  = swz >> 3;
    const int b   = mt >> 4;
    const int t0  = (mt & 15) << 8;
    const int c0  = nt << 6;

    const int srow = lane >> 2;           // staging: lane -> row in unit
    const int schk = lane & 3;

    // ---- staging descriptors: 58 GLL16 units ----
    // g<17: Ahi, 17..33: Alo, 34..57: B (dt x tap x u). Unit g -> wave g&3.
    int sgoff[15], sloff[15];
    #pragma unroll
    for (int j = 0; j < 15; j++) {
        const int g = w + 4 * j;
        int so = 137953344, lo = 0;
        if (g < 58) {
            if (g < 34) {                              // A units
                const int dt = (g >= 17);              // 0=hi 1=lo
                const int u  = dt ? g - 17 : g;
                const int r  = 16 * u + srow;          // LDS row 0..271
                const int t  = t0 - 1 + r;
                const int sw = (schk ^ ((r >> 1) & 3)) << 4;  // pre-swizzled
                so = (t >= 0 && t < TT) ? (dt ? 67108864 : 0)
                                          + (b * TT + t) * 1024 + sw
                                        : 137953344 + sw;
                lo = dt * 17408 + u * 1024;
            } else {                                   // B units
                const int h  = g - 34;
                const int dt = h / 12;
                const int rm = h % 12;
                const int tp = rm >> 2;
                const int u  = rm & 3;
                const int r  = 16 * u + srow;
                const int sw = (schk ^ ((r >> 1) & 3)) << 4;
                so = (dt ? 135790592 : 134217728) + tp * 524288
                     + (c0 + r) * 1024 + sw;
                lo = 34816 + dt * 12288 + tp * 4096 + u * 1024;
            }
        }
        sgoff[j] = so;
        sloff[j] = lo;
    }

    // ---- LDS frag read offsets (salt-matched swizzle) ----
    int aoff[12], boff[4];
    #pragma unroll
    for (int tap = 0; tap < 3; tap++)
        #pragma unroll
        for (int i = 0; i < 4; i++) {
            const int ra = 64 * w + 16 * i + (lane & 15) + tap;
            aoff[tap * 4 + i] = ra * 64
                + (((lane >> 4) ^ ((ra >> 1) & 3)) << 4);
        }
    #pragma unroll
    for (int i = 0; i < 4; i++) {
        const int rb = 16 * i + (lane & 15);
        boff[i] = rb * 64 + (((lane >> 4) ^ ((rb >> 1) & 3)) << 4);
    }

    floatx4 acc[4][4];
    #pragma unroll
    for (int mi = 0; mi < 4; mi++)
        #pragma unroll
        for (int ni = 0; ni < 4; ni++)
            acc[mi][ni] = (floatx4)(0.f);

    // epilogue constants: col n = c0 + 16*ni + (lane&15)
    float u_n[4], cb_n[4];
    #pragma unroll
    for (int ni = 0; ni < 4; ni++) {
        int n = c0 + 16 * ni + (lane & 15);
        u_n[ni]  = out_w[n];
        cb_n[ni] = conv_b[n];
    }

    for (int kc = 0; kc < 16; kc++) {
        const int kb = kc << 6;           // 32 f16 = 64 B per k-chunk

        // ---- stage all operands (58 units across 4 waves) ----
        #pragma unroll
        for (int j = 0; j < 15; j++)
            if (w + 4 * j < 58)
                GLL16(wsb + (size_t)(sgoff[j] + kb), lds + sloff[j]);
        __syncthreads();

        // ---- compute: 3 taps x (Ahi*Bhi + Alo*Bhi + Ahi*Blo) ----
        #pragma unroll
        for (int tap = 0; tap < 3; tap++) {
            half8 ah[4], al[4], bh[4], bl[4];
            #pragma unroll
            for (int i = 0; i < 4; i++) {
                ah[i] = *(const half8*)(lds + aoff[tap * 4 + i]);
                al[i] = *(const half8*)(lds + 17408 + aoff[tap * 4 + i]);
                bh[i] = *(const half8*)(lds + 34816 + tap * 4096 + boff[i]);
                bl[i] = *(const half8*)(lds + 47104 + tap * 4096 + boff[i]);
            }
            #pragma unroll
            for (int mi = 0; mi < 4; mi++)
                #pragma unroll
                for (int ni = 0; ni < 4; ni++)
                    acc[mi][ni] = __builtin_amdgcn_mfma_f32_16x16x32_f16(
                        ah[mi], bh[ni], acc[mi][ni], 0, 0, 0);
            #pragma unroll
            for (int mi = 0; mi < 4; mi++)
                #pragma unroll
                for (int ni = 0; ni < 4; ni++)
                    acc[mi][ni] = __builtin_amdgcn_mfma_f32_16x16x32_f16(
                        al[mi], bh[ni], acc[mi][ni], 0, 0, 0);
            #pragma unroll
            for (int mi = 0; mi < 4; mi++)
                #pragma unroll
                for (int ni = 0; ni < 4; ni++)
                    acc[mi][ni] = __builtin_amdgcn_mfma_f32_16x16x32_f16(
                        ah[mi], bl[ni], acc[mi][ni], 0, 0, 0);
        }
        __syncthreads();
    }

    // epilogue: s[mi][reg] = sum_ni relu(acc + cb)*u ; reduce over lane&15 ; atomic
    float s[4][4];
    #pragma unroll
    for (int mi = 0; mi < 4; mi++)
        #pragma unroll
        for (int rg = 0; rg < 4; rg++) {
            float t = 0.f;
            #pragma unroll
            for (int ni = 0; ni < 4; ni++) {
                float y = acc[mi][ni][rg] + cb_n[ni];
                y = y > 0.f ? y : 0.f;
                t = fmaf(y, u_n[ni], t);
            }
            s[mi][rg] = t;
        }
    #pragma unroll
    for (int mi = 0; mi < 4; mi++)
        #pragma unroll
        for (int rg = 0; rg < 4; rg++) {
            #pragma unroll
            for (int off = 1; off < 16; off <<= 1)
                s[mi][rg] += __shfl_xor(s[mi][rg], off);
        }
    if ((lane & 15) == 0) {
        const int q = lane >> 4;
        #pragma unroll
        for (int mi = 0; mi < 4; mi++)
            #pragma unroll
            for (int rg = 0; rg < 4; rg++) {
                int m = 64 * w + 16 * mi + 4 * q + rg;
                atomicAdd(&a_pre[b * TT + t0 + m], s[mi][rg]);
            }
    }
}

// Per-batch: sigmoid -> token_num -> rescale -> sequential CIF scan (pipelined).
__global__ void cif_scan(const float* __restrict__ a_pre,
                         const float* __restrict__ mask,
                         const float* __restrict__ tll,
                         const float* __restrict__ out_bias,
                         float* __restrict__ out_tn,
                         float* __restrict__ out_alphas,
                         float* __restrict__ out_peak,
                         float* __restrict__ w_main,
                         int* __restrict__ fire_pos,
                         int* __restrict__ Fcount) {
    __shared__ float alpha_s[TT];
    __shared__ float wm_s[TT];
    __shared__ float fires_s[TT];
    __shared__ int   fp_s[1024];
    __shared__ double red[256];
    __shared__ float ratio_s;
    __shared__ int   F_sh;

    const int b = blockIdx.x;
    const int tid = threadIdx.x;
    const float ob = out_bias[0];

    double lsum = 0.0;
    for (int t = tid; t < TT; t += 256) {
        float a = a_pre[b * TT + t] + ob;
        float e = expf(-fabsf(a));
        float sg = (a >= 0.f) ? (1.f / (1.f + e)) : (e / (1.f + e));
        float af = sg;
        af = af > 0.f ? af : 0.f;
        af = af * mask[b * TT + t];
        alpha_s[t] = af;
        lsum += (double)af;
    }
    red[tid] = lsum;
    __syncthreads();
    for (int off = 128; off > 0; off >>= 1) {
        if (tid < off) red[tid] += red[tid + off];
        __syncthreads();
    }
    if (tid == 0) {
        float tn = (float)red[0];
        out_tn[b] = tn;
        ratio_s = tll[b] / tn;
    }
    __syncthreads();
    const float ratio = ratio_s;
    for (int t = tid; t < TT; t += 256) {
        float a = alpha_s[t] * ratio;
        alpha_s[t] = a;
        out_alphas[b * TT + t] = a;
    }
    __syncthreads();

    if (tid == 0) {
        float I = 0.f;
        int F = 0;
        float4 n0 = *(const float4*)&alpha_s[0];
        float4 n1 = *(const float4*)&alpha_s[4];
        for (int t8 = 0; t8 < TT; t8 += 8) {
            float av[8];
            *(float4*)&av[0] = n0;
            *(float4*)&av[4] = n1;
            if (t8 + 8 < TT) {
                n0 = *(const float4*)&alpha_s[t8 + 8];
                n1 = *(const float4*)&alpha_s[t8 + 12];
            }
            #pragma unroll
            for (int j = 0; j < 8; j++) {
                float a = av[j];
                float In = I + a;
                fires_s[t8 + j] = In;
                bool fire = (In >= 1.0f);
                wm_s[t8 + j] = fire ? (1.0f - I) : a;
                int Fc = (F < 1023) ? F : 1023;
                fp_s[Fc] = t8 + j;
                F += fire ? 1 : 0;
                I = fire ? (In - 1.0f) : In;
            }
        }
        F_sh = (F > 1024) ? 1024 : F;
        Fcount[b] = F_sh;
    }
    __syncthreads();
    const int F = F_sh;
    for (int t = tid; t < TT; t += 256) {
        out_peak[b * TT + t] = fires_s[t];
        w_main[b * TT + t]   = wm_s[t];
    }
    for (int s = tid; s < F; s += 256)
        fire_pos[b * 1024 + s] = fp_s[s];
}

// acoustic_embeds[b,s,:] = spill(prev fire) + sum over contiguous t-segment.
__global__ void cif_scatter(const float* __restrict__ hidden,
                            const float* __restrict__ alphas,
                            const float* __restrict__ w_main,
                            const int* __restrict__ fire_pos,
                            const int* __restrict__ Fcount,
                            float* __restrict__ out_emb) {
    const int s = blockIdx.x;
    const int b = blockIdx.y;
    const int tid = threadIdx.x;   // 0..127 -> d = 4*tid
    const int F = Fcount[b];

    float4 acc = make_float4(0.f, 0.f, 0.f, 0.f);
    if (s < F) {
        const int t_hi = fire_pos[b * 1024 + s];
        const int t_lo = (s > 0) ? fire_pos[b * 1024 + s - 1] : 0;
        for (int t = t_lo; t <= t_hi; t++) {
            float w;
            if (s > 0 && t == t_lo)
                w = alphas[b * TT + t] - w_main[b * TT + t];
            else
                w = w_main[b * TT + t];
            const float4 h = *(const float4*)(hidden + ((size_t)(b * TT + t)) * DD + 4 * tid);
            acc.x = fmaf(w, h.x, acc.x);
            acc.y = fmaf(w, h.y, acc.y);
            acc.z = fmaf(w, h.z, acc.z);
            acc.w = fmaf(w, h.w, acc.w);
        }
    }
    *(float4*)(out_emb + ((size_t)(b * LOUT + s)) * DD + 4 * tid) = acc;
}

extern "C" void kernel_launch(void* const* d_in, const int* in_sizes, int n_in,
                              void* d_out, int out_size, void* d_ws, size_t ws_size,
                              hipStream_t stream) {
    const float* hidden  = (const float*)d_in[0];
    const float* mask    = (const float*)d_in[1];
    const float* tll     = (const float*)d_in[2];
    const float* conv_w  = (const float*)d_in[3];
    const float* conv_b  = (const float*)d_in[4];
    const float* out_w   = (const float*)d_in[5];
    const float* out_b   = (const float*)d_in[6];

    float* out        = (float*)d_out;
    float* out_emb    = out;
    float* out_tn     = out + 4194304;
    float* out_alphas = out + 4194320;
    float* out_peak   = out + 4259856;

    char* ws = (char*)d_ws;
    _Float16* A_hi   = (_Float16*)(ws);
    _Float16* A_lo   = (_Float16*)(ws + 67108864);
    _Float16* B_hi   = (_Float16*)(ws + 134217728);
    _Float16* B_lo   = (_Float16*)(ws + 135790592);
    float* a_pre     = (float*)(ws + 137363456);
    float* w_main    = (float*)(ws + 137625600);
    int*   fire_pos  = (int*)(ws + 137887744);
    int*   Fcount    = (int*)(ws + 137953280);
    _Float16* zpage  = (_Float16*)(ws + 137953344);

    prep<<<16384, 256, 0, stream>>>(hidden, conv_w, A_hi, A_lo, B_hi, B_lo,
                                    a_pre, zpage);
    mfma_gemm<<<2048, 256, 0, stream>>>(ws, conv_b, out_w, a_pre);
    cif_scan<<<16, 256, 0, stream>>>(a_pre, mask, tll, out_b,
                                     out_tn, out_alphas, out_peak,
                                     w_main, fire_pos, Fcount);
    cif_scatter<<<dim3(512, 16), 128, 0, stream>>>(hidden, out_alphas, w_main,
                                                   fire_pos, Fcount, out_emb);
}

// Round 6
// 509.890 us; speedup vs baseline: 2.0106x; 1.4099x over previous
//
#include <hip/hip_runtime.h>
#include <math.h>

// Problem constants
#define BB 16
#define TT 4096
#define DD 512
#define LOUT 512

typedef __attribute__((ext_vector_type(8))) _Float16 half8;
typedef __attribute__((ext_vector_type(4))) float floatx4;

// ---------------------------------------------------------------------------
// Workspace layout (bytes):
//   A_hi    : _Float16[33554432] @ 0          (hidden hi split)
//   A_lo    : _Float16[33554432] @ 67108864   (hidden lo split)
//   B_hi    : _Float16[786432]   @ 134217728  (conv_w hi, [tap][c][i])
//   B_lo    : _Float16[786432]   @ 135790592
//   a_pre   : float[65536]       @ 137363456
//   w_main  : float[65536]       @ 137625600
//   fire_pos: int[16384]         @ 137887744
//   Fcount  : int[16]            @ 137953280
//   zpage16 : _Float16[512]      @ 137953344  (zero page, conv halo rows)
// ---------------------------------------------------------------------------

// Fused prep: split hidden -> f16 hi/lo, repack conv_w, zero a_pre + zpage.
__global__ void prep(const float* __restrict__ hidden,
                     const float* __restrict__ conv_w,
                     _Float16* __restrict__ A_hi,
                     _Float16* __restrict__ A_lo,
                     _Float16* __restrict__ B_hi,
                     _Float16* __restrict__ B_lo,
                     float* __restrict__ a_pre,
                     _Float16* __restrict__ zp) {
    int idx = blockIdx.x * 256 + threadIdx.x;    // 4194304 threads, 8 elems each
    const float4* src = (const float4*)(hidden + 8 * (size_t)idx);
    float4 v0 = src[0], v1 = src[1];
    float x[8] = {v0.x, v0.y, v0.z, v0.w, v1.x, v1.y, v1.z, v1.w};
    _Float16 hi[8], lo[8];
    #pragma unroll
    for (int j = 0; j < 8; j++) {
        hi[j] = (_Float16)x[j];
        lo[j] = (_Float16)(x[j] - (float)hi[j]);
    }
    *(half8*)(A_hi + 8 * (size_t)idx) = *(half8*)hi;
    *(half8*)(A_lo + 8 * (size_t)idx) = *(half8*)lo;

    if (idx < 786432) {                          // conv_w repack + split
        int tap = idx / 262144;
        int rem = idx - tap * 262144;
        int c = rem >> 9;
        int i = rem & 511;
        float v = conv_w[(c * 512 + i) * 3 + tap];
        _Float16 h = (_Float16)v;
        B_hi[idx] = h;
        B_lo[idx] = (_Float16)(v - (float)h);
    }
    if (idx < 65536) a_pre[idx] = 0.f;
    if (idx < 512)   zp[idx] = (_Float16)0.f;
}

#define GLL16(g, l) __builtin_amdgcn_global_load_lds( \
    (const __attribute__((address_space(1))) void*)(g), \
    (__attribute__((address_space(3))) void*)(l), 16, 0, 0)

// ---------------------------------------------------------------------------
// Split-f16 conv-GEMM. R5 kernel, harness-verified 258 us, conflicts = 0:
//   - ALL operands staged to LDS via 58 GLL16 units, single 59392 B buffer,
//     2 barriers per k-chunk, 2 blocks/CU, 16x16x32 MFMA, 4x4 frags/wave.
//   - swizzle salt ((r>>1)&3) on staging pre-swizzle + frag reads.
// Block tile 256(M) x 64(N), 4 waves, wave tile 64x64.
// LDS: Ahi @0 (272 rows x 64B), Alo @17408, Bhi @34816+tap*4096,
//      Blo @47104+tap*4096.
// ---------------------------------------------------------------------------
__launch_bounds__(256, 2)
__global__ void mfma_gemm(const char* __restrict__ wsb,
                          const float* __restrict__ conv_b,
                          const float* __restrict__ out_w,
                          float* __restrict__ a_pre) {
    __shared__ __align__(128) char lds[59392];

    const int tid  = threadIdx.x;
    const int w    = tid >> 6;            // wave 0..3 = M sub-tile
    const int lane = tid & 63;

    // XCD-chunked swizzle: all 8 N-tiles of an M-tile co-resident on one XCD.
    const int bid = blockIdx.x;
    const int swz = (bid & 7) * 256 + (bid >> 3);
    const int nt  = swz & 7;
    const int mt  = swz >> 3;
    const int b   = mt >> 4;
    const int t0  = (mt & 15) << 8;
    const int c0  = nt << 6;

    const int srow = lane >> 2;           // staging: lane -> row in unit
    const int schk = lane & 3;

    // ---- staging descriptors: 58 GLL16 units ----
    // g<17: Ahi, 17..33: Alo, 34..57: B (dt x tap x u). Unit g -> wave g&3.
    int sgoff[15], sloff[15];
    #pragma unroll
    for (int j = 0; j < 15; j++) {
        const int g = w + 4 * j;
        int so = 137953344, lo = 0;
        if (g < 58) {
            if (g < 34) {                              // A units
                const int dt = (g >= 17);              // 0=hi 1=lo
                const int u  = dt ? g - 17 : g;
                const int r  = 16 * u + srow;          // LDS row 0..271
                const int t  = t0 - 1 + r;
                const int sw = (schk ^ ((r >> 1) & 3)) << 4;  // pre-swizzled
                so = (t >= 0 && t < TT) ? (dt ? 67108864 : 0)
                                          + (b * TT + t) * 1024 + sw
                                        : 137953344 + sw;
                lo = dt * 17408 + u * 1024;
            } else {                                   // B units
                const int h  = g - 34;
                const int dt = h / 12;
                const int rm = h % 12;
                const int tp = rm >> 2;
                const int u  = rm & 3;
                const int r  = 16 * u + srow;
                const int sw = (schk ^ ((r >> 1) & 3)) << 4;
                so = (dt ? 135790592 : 134217728) + tp * 524288
                     + (c0 + r) * 1024 + sw;
                lo = 34816 + dt * 12288 + tp * 4096 + u * 1024;
            }
        }
        sgoff[j] = so;
        sloff[j] = lo;
    }

    // ---- LDS frag read offsets (salt-matched swizzle) ----
    int aoff[12], boff[4];
    #pragma unroll
    for (int tap = 0; tap < 3; tap++)
        #pragma unroll
        for (int i = 0; i < 4; i++) {
            const int ra = 64 * w + 16 * i + (lane & 15) + tap;
            aoff[tap * 4 + i] = ra * 64
                + (((lane >> 4) ^ ((ra >> 1) & 3)) << 4);
        }
    #pragma unroll
    for (int i = 0; i < 4; i++) {
        const int rb = 16 * i + (lane & 15);
        boff[i] = rb * 64 + (((lane >> 4) ^ ((rb >> 1) & 3)) << 4);
    }

    floatx4 acc[4][4];
    #pragma unroll
    for (int mi = 0; mi < 4; mi++)
        #pragma unroll
        for (int ni = 0; ni < 4; ni++)
            acc[mi][ni] = (floatx4)(0.f);

    // epilogue constants: col n = c0 + 16*ni + (lane&15)
    float u_n[4], cb_n[4];
    #pragma unroll
    for (int ni = 0; ni < 4; ni++) {
        int n = c0 + 16 * ni + (lane & 15);
        u_n[ni]  = out_w[n];
        cb_n[ni] = conv_b[n];
    }

    for (int kc = 0; kc < 16; kc++) {
        const int kb = kc << 6;           // 32 f16 = 64 B per k-chunk

        // ---- stage all operands (58 units across 4 waves) ----
        #pragma unroll
        for (int j = 0; j < 15; j++)
            if (w + 4 * j < 58)
                GLL16(wsb + (size_t)(sgoff[j] + kb), lds + sloff[j]);
        __syncthreads();

        // ---- compute: 3 taps x (Ahi*Bhi + Alo*Bhi + Ahi*Blo) ----
        #pragma unroll
        for (int tap = 0; tap < 3; tap++) {
            half8 ah[4], al[4], bh[4], bl[4];
            #pragma unroll
            for (int i = 0; i < 4; i++) {
                ah[i] = *(const half8*)(lds + aoff[tap * 4 + i]);
                al[i] = *(const half8*)(lds + 17408 + aoff[tap * 4 + i]);
                bh[i] = *(const half8*)(lds + 34816 + tap * 4096 + boff[i]);
                bl[i] = *(const half8*)(lds + 47104 + tap * 4096 + boff[i]);
            }
            #pragma unroll
            for (int mi = 0; mi < 4; mi++)
                #pragma unroll
                for (int ni = 0; ni < 4; ni++)
                    acc[mi][ni] = __builtin_amdgcn_mfma_f32_16x16x32_f16(
                        ah[mi], bh[ni], acc[mi][ni], 0, 0, 0);
            #pragma unroll
            for (int mi = 0; mi < 4; mi++)
                #pragma unroll
                for (int ni = 0; ni < 4; ni++)
                    acc[mi][ni] = __builtin_amdgcn_mfma_f32_16x16x32_f16(
                        al[mi], bh[ni], acc[mi][ni], 0, 0, 0);
            #pragma unroll
            for (int mi = 0; mi < 4; mi++)
                #pragma unroll
                for (int ni = 0; ni < 4; ni++)
                    acc[mi][ni] = __builtin_amdgcn_mfma_f32_16x16x32_f16(
                        ah[mi], bl[ni], acc[mi][ni], 0, 0, 0);
        }
        __syncthreads();
    }

    // epilogue: s[mi][reg] = sum_ni relu(acc + cb)*u ; reduce over lane&15 ; atomic
    float s[4][4];
    #pragma unroll
    for (int mi = 0; mi < 4; mi++)
        #pragma unroll
        for (int rg = 0; rg < 4; rg++) {
            float t = 0.f;
            #pragma unroll
            for (int ni = 0; ni < 4; ni++) {
                float y = acc[mi][ni][rg] + cb_n[ni];
                y = y > 0.f ? y : 0.f;
                t = fmaf(y, u_n[ni], t);
            }
            s[mi][rg] = t;
        }
    #pragma unroll
    for (int mi = 0; mi < 4; mi++)
        #pragma unroll
        for (int rg = 0; rg < 4; rg++) {
            #pragma unroll
            for (int off = 1; off < 16; off <<= 1)
                s[mi][rg] += __shfl_xor(s[mi][rg], off);
        }
    if ((lane & 15) == 0) {
        const int q = lane >> 4;
        #pragma unroll
        for (int mi = 0; mi < 4; mi++)
            #pragma unroll
            for (int rg = 0; rg < 4; rg++) {
                int m = 64 * w + 16 * mi + 4 * q + rg;
                atomicAdd(&a_pre[b * TT + t0 + m], s[mi][rg]);
            }
    }
}

// ---------------------------------------------------------------------------
// Per-batch: sigmoid -> token_num -> rescale -> PARALLEL CIF scan.
// The recurrence {I += a; if (I>=1) I -= 1} with 0 <= a < 1 has closed form
//   F_t = floor(P_t), I_t = P_t - F_t, fire_t = (F_t > F_{t-1}),
//   cur_t = fire ? F_t - P_{t-1} : a_t
// where P_t = inclusive prefix sum of alphas. P computed in double
// (per-thread 16-chunk serial + 8-step Hillis-Steele block scan) so it is
// ~exact; replaces the single-lane 4096-step serial scan.
// ---------------------------------------------------------------------------
__global__ void cif_scan(const float* __restrict__ a_pre,
                         const float* __restrict__ mask,
                         const float* __restrict__ tll,
                         const float* __restrict__ out_bias,
                         float* __restrict__ out_tn,
                         float* __restrict__ out_alphas,
                         float* __restrict__ out_peak,
                         float* __restrict__ w_main,
                         int* __restrict__ fire_pos,
                         int* __restrict__ Fcount) {
    __shared__ float alpha_s[TT];
    __shared__ float wm_s[TT];
    __shared__ float fires_s[TT];
    __shared__ int   fp_s[1024];
    __shared__ double red[256];
    __shared__ float ratio_s;
    __shared__ int   F_sh;

    const int b = blockIdx.x;
    const int tid = threadIdx.x;
    const float ob = out_bias[0];

    // ---- sigmoid + masked alphas + token_num reduction ----
    double lsum = 0.0;
    for (int t = tid; t < TT; t += 256) {
        float a = a_pre[b * TT + t] + ob;
        float e = expf(-fabsf(a));
        float sg = (a >= 0.f) ? (1.f / (1.f + e)) : (e / (1.f + e));
        float af = sg;
        af = af > 0.f ? af : 0.f;
        af = af * mask[b * TT + t];
        alpha_s[t] = af;
        lsum += (double)af;
    }
    red[tid] = lsum;
    __syncthreads();
    for (int off = 128; off > 0; off >>= 1) {
        if (tid < off) red[tid] += red[tid + off];
        __syncthreads();
    }
    if (tid == 0) {
        float tn = (float)red[0];
        out_tn[b] = tn;
        ratio_s = tll[b] / tn;
    }
    __syncthreads();
    const float ratio = ratio_s;

    // ---- rescale: thread tid owns contiguous chunk [16*tid, 16*tid+16) ----
    const int t0c = tid * 16;
    float av[16];
    double csum = 0.0;
    #pragma unroll
    for (int j = 0; j < 16; j++) {
        float a = alpha_s[t0c + j] * ratio;
        av[j] = a;
        csum += (double)a;
    }
    #pragma unroll
    for (int j = 0; j < 16; j++)
        alpha_s[t0c + j] = av[j];
    red[tid] = csum;
    __syncthreads();

    // ---- inclusive Hillis-Steele scan of 256 chunk sums (double) ----
    #pragma unroll
    for (int off = 1; off < 256; off <<= 1) {
        double v = (tid >= off) ? red[tid - off] : 0.0;
        __syncthreads();
        red[tid] += v;
        __syncthreads();
    }
    const double base = red[tid] - csum;   // exclusive prefix at chunk start

    // ---- per-chunk serial finish (all 256 threads in parallel) ----
    double P = base;
    int Fp = (int)P;                       // floor (P >= 0)
    #pragma unroll
    for (int j = 0; j < 16; j++) {
        const float a = av[j];
        const double Pp = P;
        P += (double)a;
        const int F = (int)P;
        fires_s[t0c + j] = (float)(P - (double)Fp);          // In (pre-reset)
        const bool fire = F > Fp;
        wm_s[t0c + j] = fire ? (float)((double)F - Pp) : a;  // cur
        if (fire && Fp < 1024) fp_s[Fp] = t0c + j;
        Fp = F;
    }
    if (tid == 255) {
        F_sh = (Fp > 1024) ? 1024 : Fp;
        Fcount[b] = F_sh;
    }
    __syncthreads();

    // ---- coalesced writes to global ----
    for (int t = tid; t < TT; t += 256) {
        out_alphas[b * TT + t] = alpha_s[t];
        out_peak[b * TT + t]   = fires_s[t];
        w_main[b * TT + t]     = wm_s[t];
    }
    const int F = F_sh;
    for (int s = tid; s < F; s += 256)
        fire_pos[b * 1024 + s] = fp_s[s];
}

// acoustic_embeds[b,s,:] = spill(prev fire) + sum over contiguous t-segment.
__global__ void cif_scatter(const float* __restrict__ hidden,
                            const float* __restrict__ alphas,
                            const float* __restrict__ w_main,
                            const int* __restrict__ fire_pos,
                            const int* __restrict__ Fcount,
                            float* __restrict__ out_emb) {
    const int s = blockIdx.x;
    const int b = blockIdx.y;
    const int tid = threadIdx.x;   // 0..127 -> d = 4*tid
    const int F = Fcount[b];

    float4 acc = make_float4(0.f, 0.f, 0.f, 0.f);
    if (s < F) {
        const int t_hi = fire_pos[b * 1024 + s];
        const int t_lo = (s > 0) ? fire_pos[b * 1024 + s - 1] : 0;
        for (int t = t_lo; t <= t_hi; t++) {
            float w;
            if (s > 0 && t == t_lo)
                w = alphas[b * TT + t] - w_main[b * TT + t];
            else
                w = w_main[b * TT + t];
            const float4 h = *(const float4*)(hidden + ((size_t)(b * TT + t)) * DD + 4 * tid);
            acc.x = fmaf(w, h.x, acc.x);
            acc.y = fmaf(w, h.y, acc.y);
            acc.z = fmaf(w, h.z, acc.z);
            acc.w = fmaf(w, h.w, acc.w);
        }
    }
    *(float4*)(out_emb + ((size_t)(b * LOUT + s)) * DD + 4 * tid) = acc;
}

extern "C" void kernel_launch(void* const* d_in, const int* in_sizes, int n_in,
                              void* d_out, int out_size, void* d_ws, size_t ws_size,
                              hipStream_t stream) {
    const float* hidden  = (const float*)d_in[0];
    const float* mask    = (const float*)d_in[1];
    const float* tll     = (const float*)d_in[2];
    const float* conv_w  = (const float*)d_in[3];
    const float* conv_b  = (const float*)d_in[4];
    const float* out_w   = (const float*)d_in[5];
    const float* out_b   = (const float*)d_in[6];

    float* out        = (float*)d_out;
    float* out_emb    = out;
    float* out_tn     = out + 4194304;
    float* out_alphas = out + 4194320;
    float* out_peak   = out + 4259856;

    char* ws = (char*)d_ws;
    _Float16* A_hi   = (_Float16*)(ws);
    _Float16* A_lo   = (_Float16*)(ws + 67108864);
    _Float16* B_hi   = (_Float16*)(ws + 134217728);
    _Float16* B_lo   = (_Float16*)(ws + 135790592);
    float* a_pre     = (float*)(ws + 137363456);
    float* w_main    = (float*)(ws + 137625600);
    int*   fire_pos  = (int*)(ws + 137887744);
    int*   Fcount    = (int*)(ws + 137953280);
    _Float16* zpage  = (_Float16*)(ws + 137953344);

    prep<<<16384, 256, 0, stream>>>(hidden, conv_w, A_hi, A_lo, B_hi, B_lo,
                                    a_pre, zpage);
    mfma_gemm<<<2048, 256, 0, stream>>>(ws, conv_b, out_w, a_pre);
    cif_scan<<<16, 256, 0, stream>>>(a_pre, mask, tll, out_b,
                                     out_tn, out_alphas, out_peak,
                                     w_main, fire_pos, Fcount);
    cif_scatter<<<dim3(512, 16), 128, 0, stream>>>(hidden, out_alphas, w_main,
                                                   fire_pos, Fcount, out_emb);
}